// Round 1
// baseline (1217.577 us; speedup 1.0000x reference)
//
#include <hip/hip_runtime.h>

// Problem constants
constexpr int CH   = 128;    // C
constexpr int TWOC = 256;    // 2C
constexpr int NPTS = 32768;  // N
constexpr int NB   = 8;      // B
constexpr int KC   = 2048;   // K-chunk for the Gram kernel

// ---------------- Workspace layout (floats) ----------------
// G   : [NB][256][256]   off 0          len 524288   (zeroed)
// S   : [NB][256]        off 524288     len 2048     (zeroed)
// P   : [NB][256]        off 526336     len 2048
// H   : [NB][256][256]   off 528384     len 524288
// E   : [NB][256][256]   off 1052672    len 524288
// E1  : [NB][256][256]   off 1576960    len 524288
// E2  : [NB][256][128]   off 2101248    len 262144
// ATT : [NB][256][128]   off 2363392    len 262144
// M   : [NB][128][256]   off 2625536    len 262144
// C0  : [NB][128]        off 2887680    len 1024
// total ~11.6 MB

// -----------------------------------------------------------------
// K1: G = Z Z^T (Z = [y; x], 2C x N per batch), 3 tiles (symmetry),
//     plus row-sums S. fp32, 128x128 tile per block, split-K atomics.
// -----------------------------------------------------------------
__global__ __launch_bounds__(256) void gram_kernel(
    const float* __restrict__ x, const float* __restrict__ y,
    float* __restrict__ G, float* __restrict__ S)
{
  const int t  = blockIdx.x;   // 0: y·yT (G00), 1: x·yT (G10), 2: x·xT (G11)
  const int kc = blockIdx.y;
  const int b  = blockIdx.z;
  const float* Ab = (t == 0) ? y : x;
  const float* Bb = (t == 2) ? x : y;
  const int growA = (t == 0) ? 0 : CH;
  const int gcolB = (t == 2) ? CH : 0;
  const float* Ap = Ab + (size_t)b * CH * NPTS + (size_t)kc * KC;
  const float* Bp = Bb + (size_t)b * CH * NPTS + (size_t)kc * KC;

  __shared__ __align__(16) float As[8][128];
  __shared__ __align__(16) float Bs[8][128];

  const int tid  = threadIdx.x;
  const int ti   = tid >> 4;        // 0..15
  const int tj   = tid & 15;        // 0..15
  const int lrow = tid >> 1;        // 0..127
  const int lk4  = (tid & 1) * 4;   // 0 or 4

  const float* arow = Ap + (size_t)lrow * NPTS + lk4;
  const float* brow = Bp + (size_t)lrow * NPTS + lk4;

  float acc[8][8];
  #pragma unroll
  for (int i = 0; i < 8; i++)
    #pragma unroll
    for (int j = 0; j < 8; j++) acc[i][j] = 0.f;
  float asum = 0.f;

  for (int k0 = 0; k0 < KC; k0 += 8) {
    const float4 av = *(const float4*)(arow + k0);
    const float4 bv = *(const float4*)(brow + k0);
    __syncthreads();
    As[lk4+0][lrow] = av.x; As[lk4+1][lrow] = av.y;
    As[lk4+2][lrow] = av.z; As[lk4+3][lrow] = av.w;
    Bs[lk4+0][lrow] = bv.x; Bs[lk4+1][lrow] = bv.y;
    Bs[lk4+2][lrow] = bv.z; Bs[lk4+3][lrow] = bv.w;
    asum += av.x + av.y + av.z + av.w;
    __syncthreads();
    #pragma unroll
    for (int kk = 0; kk < 8; kk++) {
      float a[8], bb[8];
      *(float4*)&a[0]  = *(const float4*)&As[kk][ti*8];
      *(float4*)&a[4]  = *(const float4*)&As[kk][ti*8+4];
      *(float4*)&bb[0] = *(const float4*)&Bs[kk][tj*8];
      *(float4*)&bb[4] = *(const float4*)&Bs[kk][tj*8+4];
      #pragma unroll
      for (int ii = 0; ii < 8; ii++)
        #pragma unroll
        for (int jj = 0; jj < 8; jj++)
          acc[ii][jj] = fmaf(a[ii], bb[jj], acc[ii][jj]);
    }
  }

  float* Gp = G + ((size_t)b * TWOC + growA) * TWOC + gcolB;
  #pragma unroll
  for (int ii = 0; ii < 8; ii++)
    #pragma unroll
    for (int jj = 0; jj < 8; jj++)
      atomicAdd(&Gp[(size_t)(ti*8+ii) * TWOC + (tj*8+jj)], acc[ii][jj]);

  if (t == 0)      atomicAdd(&S[b*TWOC + lrow],      asum);
  else if (t == 2) atomicAdd(&S[b*TWOC + CH + lrow], asum);
}

// -----------------------------------------------------------------
// K2a: P = W_con * S  and  mirror G01 = G10^T
// -----------------------------------------------------------------
__global__ void pmirror_kernel(const float* __restrict__ S, const float* __restrict__ qw,
                               const float* __restrict__ kw, float* __restrict__ P,
                               float* __restrict__ G)
{
  const int b = blockIdx.x;
  const int tid = threadIdx.x;  // 0..255
  const float* w = (tid < CH) ? (qw + (size_t)tid*CH) : (kw + (size_t)(tid-CH)*CH);
  const float* s = S + b*TWOC + ((tid < CH) ? 0 : CH);
  float acc = 0.f;
  for (int j = 0; j < CH; j++) acc = fmaf(w[j], s[j], acc);
  P[b*TWOC + tid] = acc;

  float* Gb = G + (size_t)b * TWOC * TWOC;
  for (int idx = tid; idx < CH*CH; idx += 256) {
    const int i2 = idx >> 7, j2 = idx & 127;
    Gb[(size_t)i2*TWOC + CH + j2] = Gb[(size_t)(CH + j2)*TWOC + i2];
  }
}

// -----------------------------------------------------------------
// K2b: H = W_con * G   (block-diagonal W_con, K=128 per row)
// -----------------------------------------------------------------
__global__ void h_kernel(const float* __restrict__ G, const float* __restrict__ qw,
                         const float* __restrict__ kw, float* __restrict__ H)
{
  const int i = blockIdx.x, b = blockIdx.y, k = threadIdx.x;  // k: 0..255
  const float* w = (i < CH) ? (qw + (size_t)i*CH) : (kw + (size_t)(i-CH)*CH);
  const int jbase = (i < CH) ? 0 : CH;
  const float* g = G + ((size_t)b*TWOC + jbase)*TWOC + k;
  float acc = 0.f;
  for (int j = 0; j < CH; j++) acc = fmaf(w[j], g[(size_t)j*TWOC], acc);
  H[((size_t)b*TWOC + i)*TWOC + k] = acc;
}

// -----------------------------------------------------------------
// K2c: E = (H * W_con^T + P b^T + b P^T + N b b^T) / 16
// -----------------------------------------------------------------
__global__ void e_kernel(const float* __restrict__ H, const float* __restrict__ qw,
                         const float* __restrict__ kw, const float* __restrict__ qb,
                         const float* __restrict__ kb, const float* __restrict__ P,
                         float* __restrict__ E)
{
  const int i = blockIdx.x, b = blockIdx.y, j = threadIdx.x;
  const float* h = H + ((size_t)b*TWOC + i)*TWOC + ((j < CH) ? 0 : CH);
  const float* w = (j < CH) ? (qw + (size_t)j*CH) : (kw + (size_t)(j-CH)*CH);
  const float bcj = (j < CH) ? qb[j] : kb[j-CH];
  const float bci = (i < CH) ? qb[i] : kb[i-CH];
  const float4* h4 = (const float4*)h;
  const float4* w4 = (const float4*)w;
  float acc = 0.f;
  for (int k = 0; k < CH/4; k++) {
    const float4 hv = h4[k], wv = w4[k];
    acc += hv.x*wv.x + hv.y*wv.y + hv.z*wv.z + hv.w*wv.w;
  }
  acc += P[b*TWOC+i]*bcj + bci*P[b*TWOC+j] + (float)NPTS * bci * bcj;
  E[((size_t)b*TWOC + i)*TWOC + j] = acc * (1.0f/16.0f);
}

// -----------------------------------------------------------------
// K2d: E1 = relu(E @ t1_w^T + t1_b)
// -----------------------------------------------------------------
__global__ void t1_kernel(const float* __restrict__ E, const float* __restrict__ t1w,
                          const float* __restrict__ t1b, float* __restrict__ E1)
{
  const int i = blockIdx.x, b = blockIdx.y, j = threadIdx.x;
  const float4* e4 = (const float4*)(E + ((size_t)b*TWOC + i)*TWOC);
  const float4* w4 = (const float4*)(t1w + (size_t)j*TWOC);
  float acc = t1b[j];
  for (int k = 0; k < TWOC/4; k++) {
    const float4 ev = e4[k], wv = w4[k];
    acc += ev.x*wv.x + ev.y*wv.y + ev.z*wv.z + ev.w*wv.w;
  }
  E1[((size_t)b*TWOC + i)*TWOC + j] = fmaxf(acc, 0.f);
}

// -----------------------------------------------------------------
// K2e: E2 = relu(E1 @ t2_w^T + t2_b)   (256 -> 128)
// -----------------------------------------------------------------
__global__ void t2_kernel(const float* __restrict__ E1, const float* __restrict__ t2w,
                          const float* __restrict__ t2b, float* __restrict__ E2)
{
  const int i = blockIdx.x, b = blockIdx.y, j = threadIdx.x;  // j: 0..127
  const float4* e4 = (const float4*)(E1 + ((size_t)b*TWOC + i)*TWOC);
  const float4* w4 = (const float4*)(t2w + (size_t)j*TWOC);
  float acc = t2b[j];
  for (int k = 0; k < TWOC/4; k++) {
    const float4 ev = e4[k], wv = w4[k];
    acc += ev.x*wv.x + ev.y*wv.y + ev.z*wv.z + ev.w*wv.w;
  }
  E2[((size_t)b*TWOC + i)*CH + j] = fmaxf(acc, 0.f);
}

// -----------------------------------------------------------------
// K2f: ATT = softmax(E2) over last dim (128), one thread per row
// -----------------------------------------------------------------
__global__ void softmax_kernel(const float* __restrict__ E2, float* __restrict__ ATT)
{
  const int b = blockIdx.x;
  const int i = threadIdx.x;  // 0..255
  const float* r = E2  + ((size_t)b*TWOC + i)*CH;
  float*       o = ATT + ((size_t)b*TWOC + i)*CH;
  float m = -1e30f;
  for (int j = 0; j < CH; j++) m = fmaxf(m, r[j]);
  float s = 0.f;
  for (int j = 0; j < CH; j++) s += expf(r[j] - m);
  const float inv = 1.f / s;
  for (int j = 0; j < CH; j++) o[j] = expf(r[j] - m) * inv;
}

// -----------------------------------------------------------------
// K2g: M = ATT^T U  (per batch 128x256), C0 = ATT^T u_b
//   columns j<128 multiply y via v2_w; j>=128 multiply x via v1_w
// -----------------------------------------------------------------
__global__ void mout_kernel(const float* __restrict__ ATT, const float* __restrict__ v1w,
                            const float* __restrict__ v2w, const float* __restrict__ v1b,
                            const float* __restrict__ v2b, float* __restrict__ M,
                            float* __restrict__ C0)
{
  const int c = blockIdx.x, b = blockIdx.y, j = threadIdx.x;  // j: 0..255
  __shared__ float acol[TWOC];
  acol[j] = ATT[((size_t)b*TWOC + j)*CH + c];
  __syncthreads();
  float acc = 0.f;
  if (j < CH) {
    for (int d = 0; d < CH; d++) acc = fmaf(acol[d], v2w[(size_t)d*CH + j], acc);
  } else {
    const int jj = j - CH;
    for (int d = 0; d < CH; d++) acc = fmaf(acol[CH + d], v1w[(size_t)d*CH + jj], acc);
  }
  M[((size_t)b*CH + c)*TWOC + j] = acc;
  if (j == 0) {
    float s = 0.f;
    for (int d = 0; d < CH; d++) s += acol[d]*v2b[d] + acol[CH+d]*v1b[d];
    C0[b*CH + c] = s;
  }
}

// -----------------------------------------------------------------
// K3: out[b] = M[b] (128x256) @ Z[b] (256xN) + C0 broadcast
//   per block: 128 x 64 output tile, K chunked by 64
// -----------------------------------------------------------------
__global__ __launch_bounds__(256) void out_kernel(
    const float* __restrict__ x, const float* __restrict__ y,
    const float* __restrict__ M, const float* __restrict__ C0,
    float* __restrict__ out)
{
  const int b  = blockIdx.y;
  const int n0 = blockIdx.x * 64;
  const int tid = threadIdx.x;
  const int tc = tid & 15;   // c-group: c = tc*8 + ii
  const int tn = tid >> 4;   // n-group: n = n0 + tn*4 + jj

  __shared__ __align__(16) float Ms[64][128];  // [k][c]
  __shared__ __align__(16) float Zs[64][64];   // [k][n]

  float acc[8][4];
  #pragma unroll
  for (int i = 0; i < 8; i++)
    #pragma unroll
    for (int j = 0; j < 4; j++) acc[i][j] = 0.f;

  const float* Mb = M + (size_t)b * CH * TWOC;

  for (int chunk = 0; chunk < 4; chunk++) {
    const int kbase = chunk * 64;
    const float* Zsrc = ((chunk < 2) ? y : x) + (size_t)b * CH * NPTS
                        + (size_t)((chunk & 1) * 64) * NPTS;
    __syncthreads();
    {
      // stage M chunk: Ms[kk][c] = Mb[c][kbase+kk]
      const int c   = tid >> 1;
      const int kb2 = (tid & 1) * 32;
      const float* mr = Mb + (size_t)c * TWOC + kbase + kb2;
      #pragma unroll
      for (int q = 0; q < 8; q++) {
        const float4 v = *(const float4*)(mr + q*4);
        Ms[kb2 + q*4 + 0][c] = v.x;
        Ms[kb2 + q*4 + 1][c] = v.y;
        Ms[kb2 + q*4 + 2][c] = v.z;
        Ms[kb2 + q*4 + 3][c] = v.w;
      }
      // stage Z chunk: Zs[kk][nn] = Zsrc[kk][n0+nn]
      const int kk  = tid >> 2;
      const int nb4 = (tid & 3) * 4;
      const float* zr = Zsrc + (size_t)kk * NPTS + n0 + nb4;
      #pragma unroll
      for (int q = 0; q < 4; q++)
        *(float4*)&Zs[kk][nb4 + q*16] = *(const float4*)(zr + q*16);
    }
    __syncthreads();
    #pragma unroll 8
    for (int kk = 0; kk < 64; kk++) {
      float a[8], zz[4];
      *(float4*)&a[0]  = *(const float4*)&Ms[kk][tc*8];
      *(float4*)&a[4]  = *(const float4*)&Ms[kk][tc*8+4];
      *(float4*)&zz[0] = *(const float4*)&Zs[kk][tn*4];
      #pragma unroll
      for (int ii = 0; ii < 8; ii++)
        #pragma unroll
        for (int jj = 0; jj < 4; jj++)
          acc[ii][jj] = fmaf(a[ii], zz[jj], acc[ii][jj]);
    }
  }

  #pragma unroll
  for (int ii = 0; ii < 8; ii++) {
    const int c = tc*8 + ii;
    const float cv = C0[b*CH + c];
    float4 o;
    o.x = acc[ii][0] + cv; o.y = acc[ii][1] + cv;
    o.z = acc[ii][2] + cv; o.w = acc[ii][3] + cv;
    *(float4*)&out[((size_t)b*CH + c)*NPTS + n0 + tn*4] = o;
  }
}

// -----------------------------------------------------------------
extern "C" void kernel_launch(void* const* d_in, const int* in_sizes, int n_in,
                              void* d_out, int out_size, void* d_ws, size_t ws_size,
                              hipStream_t stream)
{
  const float* x   = (const float*)d_in[0];
  const float* y   = (const float*)d_in[1];
  const float* qw  = (const float*)d_in[2];
  const float* qb  = (const float*)d_in[3];
  const float* kw  = (const float*)d_in[4];
  const float* kb  = (const float*)d_in[5];
  const float* v1w = (const float*)d_in[6];
  const float* v1b = (const float*)d_in[7];
  const float* v2w = (const float*)d_in[8];
  const float* v2b = (const float*)d_in[9];
  const float* t1w = (const float*)d_in[10];
  const float* t1b = (const float*)d_in[11];
  const float* t2w = (const float*)d_in[12];
  const float* t2b = (const float*)d_in[13];

  float* ws = (float*)d_ws;
  float* G  = ws + 0;
  float* S  = ws + 524288;
  float* P  = ws + 526336;
  float* H  = ws + 528384;
  float* E  = ws + 1052672;
  float* E1 = ws + 1576960;
  float* E2 = ws + 2101248;
  float* AT = ws + 2363392;
  float* Mo = ws + 2625536;
  float* C0 = ws + 2887680;
  float* outp = (float*)d_out;

  // zero G and S (ws is poisoned before every timed call)
  hipMemsetAsync(d_ws, 0, (size_t)(524288 + 2048) * sizeof(float), stream);

  gram_kernel  <<<dim3(3, NPTS/KC, NB), 256, 0, stream>>>(x, y, G, S);
  pmirror_kernel<<<dim3(NB),            256, 0, stream>>>(S, qw, kw, P, G);
  h_kernel     <<<dim3(TWOC, NB),       256, 0, stream>>>(G, qw, kw, H);
  e_kernel     <<<dim3(TWOC, NB),       256, 0, stream>>>(H, qw, kw, qb, kb, P, E);
  t1_kernel    <<<dim3(TWOC, NB),       256, 0, stream>>>(E, t1w, t1b, E1);
  t2_kernel    <<<dim3(TWOC, NB),       128, 0, stream>>>(E1, t2w, t2b, E2);
  softmax_kernel<<<dim3(NB),            256, 0, stream>>>(E2, AT);
  mout_kernel  <<<dim3(CH, NB),         256, 0, stream>>>(AT, v1w, v2w, v1b, v2b, Mo, C0);
  out_kernel   <<<dim3(NPTS/64, NB),    256, 0, stream>>>(x, y, Mo, C0, outp);
}

// Round 2
// 802.288 us; speedup vs baseline: 1.5176x; 1.5176x over previous
//
#include <hip/hip_runtime.h>

// Problem constants
constexpr int CH   = 128;    // C
constexpr int TWOC = 256;    // 2C
constexpr int NPTS = 32768;  // N
constexpr int NB   = 8;      // B
constexpr int KC   = 2048;   // K-chunk for the Gram kernels (split-K)

typedef _Float16 half8 __attribute__((ext_vector_type(8)));
typedef float floatx4 __attribute__((ext_vector_type(4)));

// ---------------- Workspace layout (float offsets) ----------------
// G   : 0        len 524288   (zeroed)
// S   : 524288   len 2048     (zeroed)
// P   : 526336   len 2048
// H   : 528384   len 524288
// E   : 1052672  len 524288
// E1  : 1576960  len 524288
// E2  : 2101248  len 262144
// ATT : 2363392  len 262144
// C0  : 2625536  len 1024
// MH  : 2626560  len 131072 floats (= 262144 f16)   [fallback: fp32 M, 262144 floats]
// ZH  : 2757632  len 33554432 floats (= 67108864 f16)  [new path only]
constexpr size_t OFF_G  = 0;
constexpr size_t OFF_S  = 524288;
constexpr size_t OFF_P  = 526336;
constexpr size_t OFF_H  = 528384;
constexpr size_t OFF_E  = 1052672;
constexpr size_t OFF_E1 = 1576960;
constexpr size_t OFF_E2 = 2101248;
constexpr size_t OFF_AT = 2363392;
constexpr size_t OFF_C0 = 2625536;
constexpr size_t OFF_MH = 2626560;
constexpr size_t OFF_ZH = 2757632;
constexpr size_t WS_NEED_NEW = (OFF_ZH + 33554432) * sizeof(float);  // ~145.2 MB

// =================================================================
// NEW PATH (f16 MFMA)
// =================================================================

// Convert: Z = [y; x] per batch -> f16, plus row sums S (atomic).
__global__ __launch_bounds__(256) void convert_kernel(
    const float* __restrict__ x, const float* __restrict__ y,
    _Float16* __restrict__ Zh, float* __restrict__ S)
{
  const int seg = blockIdx.x;          // 0..7 (4096 elements each)
  const int r   = blockIdx.y;          // 0..255
  const int b   = blockIdx.z;
  const float* src = ((r < CH) ? (y + ((size_t)b*CH + r)*NPTS)
                               : (x + ((size_t)b*CH + (r-CH))*NPTS)) + (size_t)seg*4096;
  _Float16* dst = Zh + ((size_t)b*TWOC + r)*NPTS + (size_t)seg*4096;
  const int tid = threadIdx.x;

  float s = 0.f;
  const float4* s4 = (const float4*)(src + tid*16);
  union { uint4 u; _Float16 h[8]; } p0, p1;
  float4 a = s4[0], bq = s4[1], c = s4[2], d = s4[3];
  p0.h[0]=(_Float16)a.x;  p0.h[1]=(_Float16)a.y;  p0.h[2]=(_Float16)a.z;  p0.h[3]=(_Float16)a.w;
  p0.h[4]=(_Float16)bq.x; p0.h[5]=(_Float16)bq.y; p0.h[6]=(_Float16)bq.z; p0.h[7]=(_Float16)bq.w;
  p1.h[0]=(_Float16)c.x;  p1.h[1]=(_Float16)c.y;  p1.h[2]=(_Float16)c.z;  p1.h[3]=(_Float16)c.w;
  p1.h[4]=(_Float16)d.x;  p1.h[5]=(_Float16)d.y;  p1.h[6]=(_Float16)d.z;  p1.h[7]=(_Float16)d.w;
  s += a.x+a.y+a.z+a.w + bq.x+bq.y+bq.z+bq.w + c.x+c.y+c.z+c.w + d.x+d.y+d.z+d.w;
  *(uint4*)(dst + tid*16)     = p0.u;
  *(uint4*)(dst + tid*16 + 8) = p1.u;

  for (int off = 32; off > 0; off >>= 1) s += __shfl_down(s, off);
  if ((tid & 63) == 0) atomicAdd(&S[b*TWOC + r], s);
}

// Gram via MFMA f16: 3 tiles (G00, G10, G11), split-K atomics into fp32 G.
// LDS: XOR-swizzled at 16B granules (g ^= row&7) -> conflict-free stages & frags.
__global__ __launch_bounds__(256) void gram_mfma(
    const _Float16* __restrict__ Zh, float* __restrict__ G)
{
  const int t  = blockIdx.x;   // 0:(0,0) 1:(128,0) 2:(128,128)
  const int kc = blockIdx.y;   // split-K chunk
  const int b  = blockIdx.z;
  const int i0 = (t == 0) ? 0 : CH;
  const int j0 = (t == 2) ? CH : 0;
  const _Float16* Ar = Zh + ((size_t)b*TWOC + i0)*NPTS + (size_t)kc*KC;
  const _Float16* Br = Zh + ((size_t)b*TWOC + j0)*NPTS + (size_t)kc*KC;

  __shared__ __align__(16) _Float16 As[128*64];
  __shared__ __align__(16) _Float16 Bs[128*64];

  const int tid   = threadIdx.x;
  const int lane  = tid & 63;
  const int wave  = tid >> 6;
  const int mbase = (wave & 1) * 64;
  const int nbase = (wave >> 1) * 64;
  const int m0    = lane & 15;
  const int quad  = lane >> 4;

  const int srow  = tid >> 1;         // staging row 0..127
  const int gbase = (tid & 1) * 4;    // granule base 0 or 4

  floatx4 acc[4][4];
  #pragma unroll
  for (int i = 0; i < 4; i++)
    #pragma unroll
    for (int j = 0; j < 4; j++) acc[i][j] = (floatx4){0.f,0.f,0.f,0.f};

  for (int k0 = 0; k0 < KC; k0 += 64) {
    uint4 av[4], bv[4];
    #pragma unroll
    for (int q = 0; q < 4; q++) {
      const int g = gbase + q;
      av[q] = *(const uint4*)(Ar + (size_t)srow*NPTS + k0 + g*8);
      bv[q] = *(const uint4*)(Br + (size_t)srow*NPTS + k0 + g*8);
    }
    __syncthreads();
    #pragma unroll
    for (int q = 0; q < 4; q++) {
      const int g  = gbase + q;
      const int gp = g ^ (srow & 7);
      *(uint4*)&As[(size_t)(srow*8 + gp)*8] = av[q];
      *(uint4*)&Bs[(size_t)(srow*8 + gp)*8] = bv[q];
    }
    __syncthreads();
    #pragma unroll
    for (int ks = 0; ks < 2; ks++) {
      half8 af[4], bf[4];
      #pragma unroll
      for (int i = 0; i < 4; i++) {
        const int ra = mbase + i*16 + m0;
        const int ga = (ks*4 + quad) ^ (ra & 7);
        af[i] = *(const half8*)&As[(size_t)(ra*8 + ga)*8];
        const int rb = nbase + i*16 + m0;
        const int gb = (ks*4 + quad) ^ (rb & 7);
        bf[i] = *(const half8*)&Bs[(size_t)(rb*8 + gb)*8];
      }
      #pragma unroll
      for (int i = 0; i < 4; i++)
        #pragma unroll
        for (int j = 0; j < 4; j++)
          acc[i][j] = __builtin_amdgcn_mfma_f32_16x16x32_f16(af[i], bf[j], acc[i][j], 0, 0, 0);
    }
  }

  // Epilogue: C/D layout col=lane&15, row=quad*4+reg (verified m89/m91)
  #pragma unroll
  for (int i = 0; i < 4; i++)
    #pragma unroll
    for (int j = 0; j < 4; j++)
      #pragma unroll
      for (int rg = 0; rg < 4; rg++) {
        const int row = i0 + mbase + i*16 + quad*4 + rg;
        const int col = j0 + nbase + j*16 + m0;
        atomicAdd(&G[((size_t)b*TWOC + row)*TWOC + col], acc[i][j][rg]);
      }
}

// out = M(128x256,f16) @ Z(256xN,f16) + C0 via MFMA.
// B operand needs d-contiguity -> u16-transpose stage into Bs[n][d] (stride 72).
__global__ __launch_bounds__(256) void out_mfma(
    const _Float16* __restrict__ Zh, const _Float16* __restrict__ Mh,
    const float* __restrict__ C0, float* __restrict__ out)
{
  const int n0 = blockIdx.x * 128;
  const int b  = blockIdx.y;

  __shared__ __align__(16) _Float16 As[128*64];   // M slice [c][d], swizzled
  __shared__ __align__(16) _Float16 Bs[128*72];   // Z^T slice [n][d], pad stride 72

  const int tid   = threadIdx.x;
  const int lane  = tid & 63;
  const int wave  = tid >> 6;
  const int mbase = (wave & 1) * 64;   // c
  const int nbase = (wave >> 1) * 64;  // n
  const int m0    = lane & 15;
  const int quad  = lane >> 4;

  const int srow  = tid >> 1;
  const int gbase = (tid & 1) * 4;
  const int dl    = tid >> 4;          // 0..15
  const int ng    = tid & 15;          // 0..15

  floatx4 acc[4][4];
  #pragma unroll
  for (int i = 0; i < 4; i++)
    #pragma unroll
    for (int j = 0; j < 4; j++) acc[i][j] = (floatx4){0.f,0.f,0.f,0.f};

  for (int d0 = 0; d0 < TWOC; d0 += 64) {
    __syncthreads();
    // stage A (M slice), swizzled granules
    #pragma unroll
    for (int q = 0; q < 4; q++) {
      const int g  = gbase + q;
      const int gp = g ^ (srow & 7);
      *(uint4*)&As[(size_t)(srow*8 + gp)*8] =
          *(const uint4*)(Mh + ((size_t)b*CH + srow)*TWOC + d0 + g*8);
    }
    // stage B transposed: Bs[n][d] <- Zh[d0+d][n0+n]
    #pragma unroll
    for (int ds = 0; ds < 4; ds++) {
      const int d = dl + ds*16;
      union { uint4 u; _Float16 h[8]; } v;
      v.u = *(const uint4*)(Zh + ((size_t)b*TWOC + d0 + d)*NPTS + n0 + ng*8);
      #pragma unroll
      for (int e = 0; e < 8; e++)
        Bs[(size_t)(ng*8 + e)*72 + d] = v.h[e];
    }
    __syncthreads();
    #pragma unroll
    for (int ks = 0; ks < 2; ks++) {
      half8 af[4], bf[4];
      #pragma unroll
      for (int i = 0; i < 4; i++) {
        const int ra = mbase + i*16 + m0;
        const int ga = (ks*4 + quad) ^ (ra & 7);
        af[i] = *(const half8*)&As[(size_t)(ra*8 + ga)*8];
        const int rn = nbase + i*16 + m0;
        bf[i] = *(const half8*)&Bs[(size_t)rn*72 + ks*32 + quad*8];
      }
      #pragma unroll
      for (int i = 0; i < 4; i++)
        #pragma unroll
        for (int j = 0; j < 4; j++)
          acc[i][j] = __builtin_amdgcn_mfma_f32_16x16x32_f16(af[i], bf[j], acc[i][j], 0, 0, 0);
    }
  }

  #pragma unroll
  for (int i = 0; i < 4; i++) {
    #pragma unroll
    for (int rg = 0; rg < 4; rg++) {
      const int c  = mbase + i*16 + quad*4 + rg;
      const float cv = C0[b*CH + c];
      #pragma unroll
      for (int j = 0; j < 4; j++) {
        const int n = n0 + nbase + j*16 + m0;
        out[((size_t)b*CH + c)*NPTS + n] = acc[i][j][rg] + cv;
      }
    }
  }
}

// mout variant writing f16 M
__global__ void mout_f16_kernel(const float* __restrict__ ATT, const float* __restrict__ v1w,
                                const float* __restrict__ v2w, const float* __restrict__ v1b,
                                const float* __restrict__ v2b, _Float16* __restrict__ Mh,
                                float* __restrict__ C0)
{
  const int c = blockIdx.x, b = blockIdx.y, j = threadIdx.x;  // j: 0..255
  __shared__ float acol[TWOC];
  acol[j] = ATT[((size_t)b*TWOC + j)*CH + c];
  __syncthreads();
  float acc = 0.f;
  if (j < CH) {
    for (int d = 0; d < CH; d++) acc = fmaf(acol[d], v2w[(size_t)d*CH + j], acc);
  } else {
    const int jj = j - CH;
    for (int d = 0; d < CH; d++) acc = fmaf(acol[CH + d], v1w[(size_t)d*CH + jj], acc);
  }
  Mh[((size_t)b*CH + c)*TWOC + j] = (_Float16)acc;
  if (j == 0) {
    float s = 0.f;
    for (int d = 0; d < CH; d++) s += acol[d]*v2b[d] + acol[CH+d]*v1b[d];
    C0[b*CH + c] = s;
  }
}

// =================================================================
// SHARED small-chain kernels (both paths)
// =================================================================
__global__ void pmirror_kernel(const float* __restrict__ S, const float* __restrict__ qw,
                               const float* __restrict__ kw, float* __restrict__ P,
                               float* __restrict__ G)
{
  const int b = blockIdx.x;
  const int tid = threadIdx.x;
  const float* w = (tid < CH) ? (qw + (size_t)tid*CH) : (kw + (size_t)(tid-CH)*CH);
  const float* s = S + b*TWOC + ((tid < CH) ? 0 : CH);
  float acc = 0.f;
  for (int j = 0; j < CH; j++) acc = fmaf(w[j], s[j], acc);
  P[b*TWOC + tid] = acc;

  float* Gb = G + (size_t)b * TWOC * TWOC;
  for (int idx = tid; idx < CH*CH; idx += 256) {
    const int i2 = idx >> 7, j2 = idx & 127;
    Gb[(size_t)i2*TWOC + CH + j2] = Gb[(size_t)(CH + j2)*TWOC + i2];
  }
}

__global__ void h_kernel(const float* __restrict__ G, const float* __restrict__ qw,
                         const float* __restrict__ kw, float* __restrict__ H)
{
  const int i = blockIdx.x, b = blockIdx.y, k = threadIdx.x;
  const float* w = (i < CH) ? (qw + (size_t)i*CH) : (kw + (size_t)(i-CH)*CH);
  const int jbase = (i < CH) ? 0 : CH;
  const float* g = G + ((size_t)b*TWOC + jbase)*TWOC + k;
  float acc = 0.f;
  for (int j = 0; j < CH; j++) acc = fmaf(w[j], g[(size_t)j*TWOC], acc);
  H[((size_t)b*TWOC + i)*TWOC + k] = acc;
}

__global__ void e_kernel(const float* __restrict__ H, const float* __restrict__ qw,
                         const float* __restrict__ kw, const float* __restrict__ qb,
                         const float* __restrict__ kb, const float* __restrict__ P,
                         float* __restrict__ E)
{
  const int i = blockIdx.x, b = blockIdx.y, j = threadIdx.x;
  const float* h = H + ((size_t)b*TWOC + i)*TWOC + ((j < CH) ? 0 : CH);
  const float* w = (j < CH) ? (qw + (size_t)j*CH) : (kw + (size_t)(j-CH)*CH);
  const float bcj = (j < CH) ? qb[j] : kb[j-CH];
  const float bci = (i < CH) ? qb[i] : kb[i-CH];
  const float4* h4 = (const float4*)h;
  const float4* w4 = (const float4*)w;
  float acc = 0.f;
  for (int k = 0; k < CH/4; k++) {
    const float4 hv = h4[k], wv = w4[k];
    acc += hv.x*wv.x + hv.y*wv.y + hv.z*wv.z + hv.w*wv.w;
  }
  acc += P[b*TWOC+i]*bcj + bci*P[b*TWOC+j] + (float)NPTS * bci * bcj;
  E[((size_t)b*TWOC + i)*TWOC + j] = acc * (1.0f/16.0f);
}

__global__ void t1_kernel(const float* __restrict__ E, const float* __restrict__ t1w,
                          const float* __restrict__ t1b, float* __restrict__ E1)
{
  const int i = blockIdx.x, b = blockIdx.y, j = threadIdx.x;
  const float4* e4 = (const float4*)(E + ((size_t)b*TWOC + i)*TWOC);
  const float4* w4 = (const float4*)(t1w + (size_t)j*TWOC);
  float acc = t1b[j];
  for (int k = 0; k < TWOC/4; k++) {
    const float4 ev = e4[k], wv = w4[k];
    acc += ev.x*wv.x + ev.y*wv.y + ev.z*wv.z + ev.w*wv.w;
  }
  E1[((size_t)b*TWOC + i)*TWOC + j] = fmaxf(acc, 0.f);
}

__global__ void t2_kernel(const float* __restrict__ E1, const float* __restrict__ t2w,
                          const float* __restrict__ t2b, float* __restrict__ E2)
{
  const int i = blockIdx.x, b = blockIdx.y, j = threadIdx.x;
  const float4* e4 = (const float4*)(E1 + ((size_t)b*TWOC + i)*TWOC);
  const float4* w4 = (const float4*)(t2w + (size_t)j*TWOC);
  float acc = t2b[j];
  for (int k = 0; k < TWOC/4; k++) {
    const float4 ev = e4[k], wv = w4[k];
    acc += ev.x*wv.x + ev.y*wv.y + ev.z*wv.z + ev.w*wv.w;
  }
  E2[((size_t)b*TWOC + i)*CH + j] = fmaxf(acc, 0.f);
}

__global__ void softmax_kernel(const float* __restrict__ E2, float* __restrict__ ATT)
{
  const int b = blockIdx.x;
  const int i = threadIdx.x;
  const float* r = E2  + ((size_t)b*TWOC + i)*CH;
  float*       o = ATT + ((size_t)b*TWOC + i)*CH;
  float m = -1e30f;
  for (int j = 0; j < CH; j++) m = fmaxf(m, r[j]);
  float s = 0.f;
  for (int j = 0; j < CH; j++) s += expf(r[j] - m);
  const float inv = 1.f / s;
  for (int j = 0; j < CH; j++) o[j] = expf(r[j] - m) * inv;
}

// =================================================================
// FALLBACK PATH (R1 fp32 kernels, used only if ws too small)
// =================================================================
__global__ __launch_bounds__(256) void gram_kernel(
    const float* __restrict__ x, const float* __restrict__ y,
    float* __restrict__ G, float* __restrict__ S)
{
  const int t  = blockIdx.x;
  const int kc = blockIdx.y;
  const int b  = blockIdx.z;
  const float* Ab = (t == 0) ? y : x;
  const float* Bb = (t == 2) ? x : y;
  const int growA = (t == 0) ? 0 : CH;
  const int gcolB = (t == 2) ? CH : 0;
  const float* Ap = Ab + (size_t)b * CH * NPTS + (size_t)kc * KC;
  const float* Bp = Bb + (size_t)b * CH * NPTS + (size_t)kc * KC;

  __shared__ __align__(16) float As[8][128];
  __shared__ __align__(16) float Bs[8][128];

  const int tid  = threadIdx.x;
  const int ti   = tid >> 4;
  const int tj   = tid & 15;
  const int lrow = tid >> 1;
  const int lk4  = (tid & 1) * 4;

  const float* arow = Ap + (size_t)lrow * NPTS + lk4;
  const float* brow = Bp + (size_t)lrow * NPTS + lk4;

  float acc[8][8];
  #pragma unroll
  for (int i = 0; i < 8; i++)
    #pragma unroll
    for (int j = 0; j < 8; j++) acc[i][j] = 0.f;
  float asum = 0.f;

  for (int k0 = 0; k0 < KC; k0 += 8) {
    const float4 av = *(const float4*)(arow + k0);
    const float4 bv = *(const float4*)(brow + k0);
    __syncthreads();
    As[lk4+0][lrow] = av.x; As[lk4+1][lrow] = av.y;
    As[lk4+2][lrow] = av.z; As[lk4+3][lrow] = av.w;
    Bs[lk4+0][lrow] = bv.x; Bs[lk4+1][lrow] = bv.y;
    Bs[lk4+2][lrow] = bv.z; Bs[lk4+3][lrow] = bv.w;
    asum += av.x + av.y + av.z + av.w;
    __syncthreads();
    #pragma unroll
    for (int kk = 0; kk < 8; kk++) {
      float a[8], bb[8];
      *(float4*)&a[0]  = *(const float4*)&As[kk][ti*8];
      *(float4*)&a[4]  = *(const float4*)&As[kk][ti*8+4];
      *(float4*)&bb[0] = *(const float4*)&Bs[kk][tj*8];
      *(float4*)&bb[4] = *(const float4*)&Bs[kk][tj*8+4];
      #pragma unroll
      for (int ii = 0; ii < 8; ii++)
        #pragma unroll
        for (int jj = 0; jj < 8; jj++)
          acc[ii][jj] = fmaf(a[ii], bb[jj], acc[ii][jj]);
    }
  }

  float* Gp = G + ((size_t)b * TWOC + growA) * TWOC + gcolB;
  #pragma unroll
  for (int ii = 0; ii < 8; ii++)
    #pragma unroll
    for (int jj = 0; jj < 8; jj++)
      atomicAdd(&Gp[(size_t)(ti*8+ii) * TWOC + (tj*8+jj)], acc[ii][jj]);

  if (t == 0)      atomicAdd(&S[b*TWOC + lrow],      asum);
  else if (t == 2) atomicAdd(&S[b*TWOC + CH + lrow], asum);
}

__global__ void mout_f32_kernel(const float* __restrict__ ATT, const float* __restrict__ v1w,
                                const float* __restrict__ v2w, const float* __restrict__ v1b,
                                const float* __restrict__ v2b, float* __restrict__ M,
                                float* __restrict__ C0)
{
  const int c = blockIdx.x, b = blockIdx.y, j = threadIdx.x;
  __shared__ float acol[TWOC];
  acol[j] = ATT[((size_t)b*TWOC + j)*CH + c];
  __syncthreads();
  float acc = 0.f;
  if (j < CH) {
    for (int d = 0; d < CH; d++) acc = fmaf(acol[d], v2w[(size_t)d*CH + j], acc);
  } else {
    const int jj = j - CH;
    for (int d = 0; d < CH; d++) acc = fmaf(acol[CH + d], v1w[(size_t)d*CH + jj], acc);
  }
  M[((size_t)b*CH + c)*TWOC + j] = acc;
  if (j == 0) {
    float s = 0.f;
    for (int d = 0; d < CH; d++) s += acol[d]*v2b[d] + acol[CH+d]*v1b[d];
    C0[b*CH + c] = s;
  }
}

__global__ __launch_bounds__(256) void out_kernel(
    const float* __restrict__ x, const float* __restrict__ y,
    const float* __restrict__ M, const float* __restrict__ C0,
    float* __restrict__ out)
{
  const int b  = blockIdx.y;
  const int n0 = blockIdx.x * 64;
  const int tid = threadIdx.x;
  const int tc = tid & 15;
  const int tn = tid >> 4;

  __shared__ __align__(16) float Ms[64][128];
  __shared__ __align__(16) float Zs[64][64];

  float acc[8][4];
  #pragma unroll
  for (int i = 0; i < 8; i++)
    #pragma unroll
    for (int j = 0; j < 4; j++) acc[i][j] = 0.f;

  const float* Mb = M + (size_t)b * CH * TWOC;

  for (int chunk = 0; chunk < 4; chunk++) {
    const int kbase = chunk * 64;
    const float* Zsrc = ((chunk < 2) ? y : x) + (size_t)b * CH * NPTS
                        + (size_t)((chunk & 1) * 64) * NPTS;
    __syncthreads();
    {
      const int c   = tid >> 1;
      const int kb2 = (tid & 1) * 32;
      const float* mr = Mb + (size_t)c * TWOC + kbase + kb2;
      #pragma unroll
      for (int q = 0; q < 8; q++) {
        const float4 v = *(const float4*)(mr + q*4);
        Ms[kb2 + q*4 + 0][c] = v.x;
        Ms[kb2 + q*4 + 1][c] = v.y;
        Ms[kb2 + q*4 + 2][c] = v.z;
        Ms[kb2 + q*4 + 3][c] = v.w;
      }
      const int kk  = tid >> 2;
      const int nb4 = (tid & 3) * 4;
      const float* zr = Zsrc + (size_t)kk * NPTS + n0 + nb4;
      #pragma unroll
      for (int q = 0; q < 4; q++)
        *(float4*)&Zs[kk][nb4 + q*16] = *(const float4*)(zr + q*16);
    }
    __syncthreads();
    #pragma unroll 8
    for (int kk = 0; kk < 64; kk++) {
      float a[8], zz[4];
      *(float4*)&a[0]  = *(const float4*)&Ms[kk][tc*8];
      *(float4*)&a[4]  = *(const float4*)&Ms[kk][tc*8+4];
      *(float4*)&zz[0] = *(const float4*)&Zs[kk][tn*4];
      #pragma unroll
      for (int ii = 0; ii < 8; ii++)
        #pragma unroll
        for (int jj = 0; jj < 4; jj++)
          acc[ii][jj] = fmaf(a[ii], zz[jj], acc[ii][jj]);
    }
  }

  #pragma unroll
  for (int ii = 0; ii < 8; ii++) {
    const int c = tc*8 + ii;
    const float cv = C0[b*CH + c];
    float4 o;
    o.x = acc[ii][0] + cv; o.y = acc[ii][1] + cv;
    o.z = acc[ii][2] + cv; o.w = acc[ii][3] + cv;
    *(float4*)&out[((size_t)b*CH + c)*NPTS + n0 + tn*4] = o;
  }
}

// -----------------------------------------------------------------
extern "C" void kernel_launch(void* const* d_in, const int* in_sizes, int n_in,
                              void* d_out, int out_size, void* d_ws, size_t ws_size,
                              hipStream_t stream)
{
  const float* x   = (const float*)d_in[0];
  const float* y   = (const float*)d_in[1];
  const float* qw  = (const float*)d_in[2];
  const float* qb  = (const float*)d_in[3];
  const float* kw  = (const float*)d_in[4];
  const float* kb  = (const float*)d_in[5];
  const float* v1w = (const float*)d_in[6];
  const float* v1b = (const float*)d_in[7];
  const float* v2w = (const float*)d_in[8];
  const float* v2b = (const float*)d_in[9];
  const float* t1w = (const float*)d_in[10];
  const float* t1b = (const float*)d_in[11];
  const float* t2w = (const float*)d_in[12];
  const float* t2b = (const float*)d_in[13];

  float* ws = (float*)d_ws;
  float* G  = ws + OFF_G;
  float* S  = ws + OFF_S;
  float* P  = ws + OFF_P;
  float* H  = ws + OFF_H;
  float* E  = ws + OFF_E;
  float* E1 = ws + OFF_E1;
  float* E2 = ws + OFF_E2;
  float* AT = ws + OFF_AT;
  float* C0 = ws + OFF_C0;
  float* outp = (float*)d_out;

  // zero G and S
  hipMemsetAsync(d_ws, 0, (OFF_S + 2048) * sizeof(float), stream);

  if (ws_size >= WS_NEED_NEW) {
    _Float16* Mh = (_Float16*)(ws + OFF_MH);
    _Float16* Zh = (_Float16*)(ws + OFF_ZH);
    convert_kernel<<<dim3(NPTS/4096, TWOC, NB), 256, 0, stream>>>(x, y, Zh, S);
    gram_mfma     <<<dim3(3, NPTS/KC, NB),      256, 0, stream>>>(Zh, G);
    pmirror_kernel<<<dim3(NB),                  256, 0, stream>>>(S, qw, kw, P, G);
    h_kernel      <<<dim3(TWOC, NB),            256, 0, stream>>>(G, qw, kw, H);
    e_kernel      <<<dim3(TWOC, NB),            256, 0, stream>>>(H, qw, kw, qb, kb, P, E);
    t1_kernel     <<<dim3(TWOC, NB),            256, 0, stream>>>(E, t1w, t1b, E1);
    t2_kernel     <<<dim3(TWOC, NB),            128, 0, stream>>>(E1, t2w, t2b, E2);
    softmax_kernel<<<dim3(NB),                  256, 0, stream>>>(E2, AT);
    mout_f16_kernel<<<dim3(CH, NB),             256, 0, stream>>>(AT, v1w, v2w, v1b, v2b, Mh, C0);
    out_mfma      <<<dim3(NPTS/128, NB),        256, 0, stream>>>(Zh, Mh, C0, outp);
  } else {
    float* Mo = ws + OFF_MH;  // fp32 M fits in MH region (262144 floats? uses 262144) -- fallback-only
    gram_kernel   <<<dim3(3, NPTS/KC, NB), 256, 0, stream>>>(x, y, G, S);
    pmirror_kernel<<<dim3(NB),             256, 0, stream>>>(S, qw, kw, P, G);
    h_kernel      <<<dim3(TWOC, NB),       256, 0, stream>>>(G, qw, kw, H);
    e_kernel      <<<dim3(TWOC, NB),       256, 0, stream>>>(H, qw, kw, qb, kb, P, E);
    t1_kernel     <<<dim3(TWOC, NB),       256, 0, stream>>>(E, t1w, t1b, E1);
    t2_kernel     <<<dim3(TWOC, NB),       128, 0, stream>>>(E1, t2w, t2b, E2);
    softmax_kernel<<<dim3(NB),             256, 0, stream>>>(E2, AT);
    mout_f32_kernel<<<dim3(CH, NB),        256, 0, stream>>>(AT, v1w, v2w, v1b, v2b, Mo, C0);
    out_kernel    <<<dim3(NPTS/64, NB),    256, 0, stream>>>(x, y, Mo, C0, outp);
  }
}